// Round 3
// baseline (5888.318 us; speedup 1.0000x reference)
//
#include <hip/hip_runtime.h>
#include <math.h>

// ---- problem constants ----
constexpr int B_   = 64;
constexpr int S_   = 197;
constexpr int D_   = 768;
constexpr int H_   = 12;
constexpr int FF_  = 3072;
constexpr int DEPTH_ = 12;
constexpr int NP_  = 196;
constexpr int M_   = B_ * S_;    // 12608
constexpr int MP_  = B_ * NP_;   // 12544 (= 98*128)
constexpr int MPAD = 12672;      // 99*128

typedef __attribute__((ext_vector_type(8))) short  bf16x8;
typedef __attribute__((ext_vector_type(4))) float  f32x4;
typedef unsigned short ushort_t;

__device__ __forceinline__ ushort_t f2bf(float x) {
    unsigned u = __builtin_bit_cast(unsigned, x);
    unsigned r = u + 0x7FFFu + ((u >> 16) & 1u);
    return (ushort_t)(r >> 16);
}

#define GLOAD_LDS16(g, l)                                                      \
    __builtin_amdgcn_global_load_lds(                                          \
        (const __attribute__((address_space(1))) void*)(g),                    \
        (__attribute__((address_space(3))) void*)(l), 16, 0, 0)

// ====================== MFMA GEMM (2-phase dbuf + XCD swizzle) ======================
// C[M,N] = epi(A[M,K] @ Bt[N,K]^T + bias)   A,Bt bf16; acc f32.
// EPI: 0 = bf16 out, 1 = bf16 out + GELU, 2 = f32 out + residual, 3 = f32 out.
// K/64 must be EVEN (12 or 48 here).
constexpr int BM = 128, BN = 128, BK = 64;

template<int EPI>
__global__ __launch_bounds__(256)
void mm_k(const ushort_t* __restrict__ A, const ushort_t* __restrict__ Bt,
          const float* __restrict__ bias, const float* __restrict__ res,
          void* __restrict__ Cout, int M, int N, int K) {
    __shared__ __align__(16) ushort_t As[2][BM * BK];
    __shared__ __align__(16) ushort_t Bs[2][BN * BK];
    const int tid  = threadIdx.x;
    const int wid  = tid >> 6;
    const int lane = tid & 63;

    // bijective XCD-chunked swizzle (m204): each XCD gets a contiguous logical range
    const int nwg  = gridDim.x * gridDim.y;
    const int orig = blockIdx.y * gridDim.x + blockIdx.x;
    const int xcd  = orig & 7, slot = orig >> 3;
    const int q8   = nwg >> 3, r8 = nwg & 7;
    const int logical = (xcd < r8 ? xcd * (q8 + 1) : r8 * (q8 + 1) + (xcd - r8) * q8) + slot;
    const int m0 = (logical / gridDim.x) * BM;
    const int n0 = (logical % gridDim.x) * BN;
    const int wr = wid >> 1, wc = wid & 1;

    const int srow = lane >> 3;          // 0..7
    const int scol = (lane & 7) * 8;     // element col within BK

    f32x4 acc[4][4];
    #pragma unroll
    for (int m = 0; m < 4; ++m)
        #pragma unroll
        for (int n = 0; n < 4; ++n)
            acc[m][n] = (f32x4){0.f, 0.f, 0.f, 0.f};

    const size_t arow0 = (size_t)(m0 + wid * 32 + srow) * K + scol;  // chunk base rows
    const size_t brow0 = (size_t)(n0 + wid * 32 + srow) * K + scol;

    #define STAGE(buf, k0)                                                        \
        { _Pragma("unroll")                                                       \
          for (int i = 0; i < 4; ++i) {                                           \
              const int c = wid * 4 + i;                                          \
              GLOAD_LDS16(A  + arow0 + (size_t)i * 8 * K + (k0), &As[buf][c * 512]); \
              GLOAD_LDS16(Bt + brow0 + (size_t)i * 8 * K + (k0), &Bs[buf][c * 512]); \
          } }

    #define COMPUTE(buf)                                                          \
        { _Pragma("unroll")                                                       \
          for (int kk = 0; kk < 2; ++kk) {                                        \
              bf16x8 av[4], bv[4];                                                \
              _Pragma("unroll")                                                   \
              for (int m = 0; m < 4; ++m)                                         \
                  av[m] = *(const bf16x8*)&As[buf][(wr * 64 + m * 16 + (lane & 15)) * 64 + kk * 32 + (lane >> 4) * 8]; \
              _Pragma("unroll")                                                   \
              for (int n = 0; n < 4; ++n)                                         \
                  bv[n] = *(const bf16x8*)&Bs[buf][(wc * 64 + n * 16 + (lane & 15)) * 64 + kk * 32 + (lane >> 4) * 8]; \
              _Pragma("unroll")                                                   \
              for (int m = 0; m < 4; ++m)                                         \
                  _Pragma("unroll")                                               \
                  for (int n = 0; n < 4; ++n)                                     \
                      acc[m][n] = __builtin_amdgcn_mfma_f32_16x16x32_bf16(av[m], bv[n], acc[m][n], 0, 0, 0); \
          } }

    STAGE(0, 0);
    __syncthreads();                       // drains stage(0)
    for (int k0 = 0; k0 < K; k0 += 2 * BK) {
        STAGE(1, k0 + BK);                 // prefetch in flight during compute(0)
        COMPUTE(0);
        __syncthreads();                   // drains stage(1); all done reading buf0
        if (k0 + 2 * BK < K) STAGE(0, k0 + 2 * BK);
        COMPUTE(1);
        __syncthreads();                   // drains stage(0); all done reading buf1
    }
    #undef STAGE
    #undef COMPUTE

    const int cr = wr * 64 + (lane >> 4) * 4;
    const int cc = wc * 64 + (lane & 15);
    #pragma unroll
    for (int n = 0; n < 4; ++n) {
        const int col = n0 + cc + n * 16;
        const float bcol = bias[col];
        #pragma unroll
        for (int m = 0; m < 4; ++m) {
            #pragma unroll
            for (int j = 0; j < 4; ++j) {
                const int row = m0 + cr + m * 16 + j;
                float v = acc[m][n][j] + bcol;
                if (EPI == 1) v = 0.5f * v * (1.0f + erff(v * 0.70710678118654752f));
                if (EPI == 2) v += res[(size_t)row * N + col];
                if (EPI <= 1) ((ushort_t*)Cout)[(size_t)row * N + col] = f2bf(v);
                else          ((float*)Cout)[(size_t)row * N + col] = v;
            }
        }
    }
}

// ====================== MFMA attention ======================
constexpr int SKV = 224;     // padded KV length (7 k-tiles of 32)
constexpr int VLD = 232;     // padded Vt row length (elements)

__global__ __launch_bounds__(256)
void attn2_k(const ushort_t* __restrict__ qkv, ushort_t* __restrict__ o) {
    __shared__ __align__(16) ushort_t Ks[SKV * 64];   // [j][dh], XOR-swizzled
    __shared__ __align__(16) ushort_t Vt[64 * VLD];   // [dh][j]
    __shared__ __align__(16) ushort_t Pw[4 * 512];    // per-wave 16x32, swizzled
    const int h = blockIdx.x, b = blockIdx.y;
    const int tid = threadIdx.x, wid = tid >> 6, lane = tid & 63;
    const size_t baseq = (size_t)(b * S_) * 2304 + h * 64;

    {
        const int jr  = tid >> 3;          // 0..31
        const int dh0 = (tid & 7) * 8;
        for (int pass = 0; pass < 7; ++pass) {
            const int j = pass * 32 + jr;
            bf16x8 kv = {0, 0, 0, 0, 0, 0, 0, 0};
            bf16x8 vv = {0, 0, 0, 0, 0, 0, 0, 0};
            if (j < S_) {
                kv = *(const bf16x8*)&qkv[baseq + (size_t)j * 2304 + 768  + dh0];
                vv = *(const bf16x8*)&qkv[baseq + (size_t)j * 2304 + 1536 + dh0];
            }
            const int koff = (j * 128 + dh0 * 2) ^ ((j & 7) << 4);
            *(bf16x8*)((char*)Ks + koff) = kv;
            #pragma unroll
            for (int i = 0; i < 8; ++i) Vt[(dh0 + i) * VLD + j] = (ushort_t)vv[i];
        }
    }
    __syncthreads();

    char* const pwb = (char*)Pw + wid * 1024;

    for (int it = 0; it < 4; ++it) {
        int sq = it * 64 + wid * 16 + (lane & 15);
        const int sqc = (sq < S_) ? sq : (S_ - 1);
        bf16x8 qf[2];
        #pragma unroll
        for (int kk = 0; kk < 2; ++kk)
            qf[kk] = *(const bf16x8*)&qkv[baseq + (size_t)sqc * 2304 + kk * 32 + (lane >> 4) * 8];

        f32x4 sa[14];
        #pragma unroll
        for (int nf = 0; nf < 14; ++nf) sa[nf] = (f32x4){0.f, 0.f, 0.f, 0.f};
        #pragma unroll
        for (int kk = 0; kk < 2; ++kk) {
            #pragma unroll
            for (int nf = 0; nf < 14; ++nf) {
                const int j = nf * 16 + (lane & 15);
                const int off = (j * 128 + kk * 64 + (lane >> 4) * 16) ^ ((j & 7) << 4);
                bf16x8 kf = *(const bf16x8*)((const char*)Ks + off);
                sa[nf] = __builtin_amdgcn_mfma_f32_16x16x32_bf16(qf[kk], kf, sa[nf], 0, 0, 0);
            }
        }

        const int jcol = lane & 15;
        float mx[4] = {-1e30f, -1e30f, -1e30f, -1e30f};
        #pragma unroll
        for (int nf = 0; nf < 14; ++nf)
            #pragma unroll
            for (int r = 0; r < 4; ++r) mx[r] = fmaxf(mx[r], sa[nf][r]);
        float ls[4];
        #pragma unroll
        for (int r = 0; r < 4; ++r) {
            float m = mx[r] * 0.125f;
            m = fmaxf(m, __shfl_xor(m, 1, 64));
            m = fmaxf(m, __shfl_xor(m, 2, 64));
            m = fmaxf(m, __shfl_xor(m, 4, 64));
            m = fmaxf(m, __shfl_xor(m, 8, 64));
            float s = 0.f;
            #pragma unroll
            for (int nf = 0; nf < 14; ++nf) {
                const int j = nf * 16 + jcol;
                float p = (j < S_) ? exp2f((sa[nf][r] * 0.125f - m) * 1.44269504088896f) : 0.f;
                sa[nf][r] = p;
                s += p;
            }
            s += __shfl_xor(s, 1, 64);
            s += __shfl_xor(s, 2, 64);
            s += __shfl_xor(s, 4, 64);
            s += __shfl_xor(s, 8, 64);
            ls[r] = s;
        }

        f32x4 oa[4];
        #pragma unroll
        for (int nf = 0; nf < 4; ++nf) oa[nf] = (f32x4){0.f, 0.f, 0.f, 0.f};
        #pragma unroll
        for (int kt = 0; kt < 7; ++kt) {
            #pragma unroll
            for (int half = 0; half < 2; ++half) {
                #pragma unroll
                for (int r = 0; r < 4; ++r) {
                    const int qr = (lane >> 4) * 4 + r;
                    const int jl = half * 16 + jcol;
                    const int off = (qr * 64 + jl * 2) ^ (((qr >> 1) & 3) << 4);
                    *(ushort_t*)(pwb + off) = f2bf(sa[kt * 2 + half][r]);
                }
            }
            const int arow = lane & 15;
            const int aoff = (arow * 64 + (lane >> 4) * 16) ^ (((arow >> 1) & 3) << 4);
            bf16x8 pa = *(const bf16x8*)(pwb + aoff);
            #pragma unroll
            for (int nf = 0; nf < 4; ++nf) {
                const int dh = nf * 16 + (lane & 15);
                bf16x8 vb = *(const bf16x8*)((const char*)Vt + dh * (VLD * 2) + (kt * 32 + (lane >> 4) * 8) * 2);
                oa[nf] = __builtin_amdgcn_mfma_f32_16x16x32_bf16(pa, vb, oa[nf], 0, 0, 0);
            }
        }

        #pragma unroll
        for (int r = 0; r < 4; ++r) {
            const int so = it * 64 + wid * 16 + (lane >> 4) * 4 + r;
            if (so < S_) {
                const float inv = 1.0f / ls[r];
                #pragma unroll
                for (int nf = 0; nf < 4; ++nf)
                    o[(size_t)(b * S_ + so) * 768 + h * 64 + nf * 16 + (lane & 15)] = f2bf(oa[nf][r] * inv);
            }
        }
    }
}

// ====================== small kernels ======================
__global__ __launch_bounds__(256)
void tcast_k(const float* __restrict__ in, ushort_t* __restrict__ out,
             int R, int C, size_t in_ls, size_t out_ls) {
    __shared__ float t[32][33];
    const float* ip = in + (size_t)blockIdx.z * in_ls;
    ushort_t* op = out + (size_t)blockIdx.z * out_ls;
    const int c0 = blockIdx.x * 32, r0 = blockIdx.y * 32;
    const int tx = threadIdx.x & 31, ty = threadIdx.x >> 5;
    #pragma unroll
    for (int i = 0; i < 4; ++i)
        t[ty + i * 8][tx] = ip[(size_t)(r0 + ty + i * 8) * C + c0 + tx];
    __syncthreads();
    #pragma unroll
    for (int i = 0; i < 4; ++i)
        op[(size_t)(c0 + ty + i * 8) * R + r0 + tx] = f2bf(t[tx][ty + i * 8]);
}

__global__ void cast_k(const float* __restrict__ in, ushort_t* __restrict__ out, int n) {
    int i = blockIdx.x * 256 + threadIdx.x;
    if (i < n) out[i] = f2bf(in[i]);
}

__global__ void biascat_k(const float* __restrict__ qb, const float* __restrict__ kb,
                          const float* __restrict__ vb, float* __restrict__ out) {
    int i = blockIdx.x * 256 + threadIdx.x;       // l*2304 + n
    if (i >= DEPTH_ * 2304) return;
    int l = i / 2304, n = i % 2304;
    float v = (n < 768) ? qb[l * 768 + n] : (n < 1536) ? kb[l * 768 + n - 768] : vb[l * 768 + n - 1536];
    out[i] = v;
}

__global__ void zeroyb_k(ushort_t* __restrict__ yb) {
    int i = blockIdx.x * 256 + threadIdx.x;       // 64 pad rows x 768
    if (i < (MPAD - M_) * 768) yb[(size_t)M_ * 768 + i] = 0;
}

__global__ void im2col_k(const float* __restrict__ x, ushort_t* __restrict__ pm) {
    size_t idx = (size_t)blockIdx.x * 256 + threadIdx.x;
    if (idx >= (size_t)MP_ * 768) return;
    int col = (int)(idx % 768);
    int row = (int)(idx / 768);
    int b = row / NP_, p = row % NP_;
    int c = col >> 8, rem = col & 255, ky = rem >> 4, kx = rem & 15;
    int py = p / 14, px = p % 14;
    pm[idx] = f2bf(x[(((size_t)b * 3 + c) * 224 + (py * 16 + ky)) * 224 + (px * 16 + kx)]);
}

__global__ void assemble_k(const float* __restrict__ pe, const float* __restrict__ cls,
                           const float* __restrict__ pos, float* __restrict__ h) {
    size_t idx = (size_t)blockIdx.x * 256 + threadIdx.x;
    if (idx >= (size_t)MPAD * D_) return;
    int d = (int)(idx % D_);
    int row = (int)(idx / D_);
    float v = 0.f;
    if (row < M_) {
        int b = row / S_, s = row % S_;
        if (s == 0) v = cls[d] + pos[d];
        else        v = pe[((size_t)b * NP_ + (s - 1)) * D_ + d] + pos[(size_t)s * D_ + d];
    }
    h[idx] = v;
}

__device__ __forceinline__ float block_reduce_sum(float val) {
    __shared__ float sm[4];
    #pragma unroll
    for (int off = 32; off > 0; off >>= 1) val += __shfl_xor(val, off, 64);
    int wid = threadIdx.x >> 6;
    if ((threadIdx.x & 63) == 0) sm[wid] = val;
    __syncthreads();
    float r = (sm[0] + sm[1]) + (sm[2] + sm[3]);
    __syncthreads();
    return r;
}

template<bool BF16OUT>
__global__ __launch_bounds__(256)
void ln_k(const float* __restrict__ x, size_t xstride,
          void* __restrict__ y, size_t ystride,
          const float* __restrict__ s, const float* __restrict__ b) {
    const float* xr = x + (size_t)blockIdx.x * xstride;
    const int tid = threadIdx.x;
    float v[3];
    float sum = 0.f;
    #pragma unroll
    for (int t = 0; t < 3; ++t) { v[t] = xr[tid + t * 256]; sum += v[t]; }
    sum = block_reduce_sum(sum);
    const float mu = sum * (1.0f / 768.0f);
    float vs = 0.f;
    #pragma unroll
    for (int t = 0; t < 3; ++t) { float d = v[t] - mu; vs += d * d; }
    vs = block_reduce_sum(vs);
    const float rstd = rsqrtf(vs * (1.0f / 768.0f) + 1e-6f);
    #pragma unroll
    for (int t = 0; t < 3; ++t) {
        int c = tid + t * 256;
        float r = (v[t] - mu) * rstd * s[c] + b[c];
        if (BF16OUT) ((ushort_t*)y)[(size_t)blockIdx.x * ystride + c] = f2bf(r);
        else         ((float*)y)[(size_t)blockIdx.x * ystride + c] = r;
    }
}

// ====================== launch ======================
extern "C" void kernel_launch(void* const* d_in, const int* in_sizes, int n_in,
                              void* d_out, int out_size, void* d_ws, size_t ws_size,
                              hipStream_t stream) {
    const float* x       = (const float*)d_in[0];
    const float* patch_w = (const float*)d_in[1];
    const float* patch_b = (const float*)d_in[2];
    const float* cls_tok = (const float*)d_in[3];
    const float* pos_emb = (const float*)d_in[4];
    const float* ln1_s   = (const float*)d_in[5];
    const float* ln1_b   = (const float*)d_in[6];
    const float* qw      = (const float*)d_in[7];
    const float* qb      = (const float*)d_in[8];
    const float* kw      = (const float*)d_in[9];
    const float* kb      = (const float*)d_in[10];
    const float* vw      = (const float*)d_in[11];
    const float* vb      = (const float*)d_in[12];
    const float* pw      = (const float*)d_in[13];
    const float* pb      = (const float*)d_in[14];
    const float* ln2_s   = (const float*)d_in[15];
    const float* ln2_b   = (const float*)d_in[16];
    const float* fc1_w   = (const float*)d_in[17];
    const float* fc1_b   = (const float*)d_in[18];
    const float* fc2_w   = (const float*)d_in[19];
    const float* fc2_b   = (const float*)d_in[20];
    const float* lnf_s   = (const float*)d_in[21];
    const float* lnf_b   = (const float*)d_in[22];
    float* out = (float*)d_out;

    // ---- workspace layout (bytes) ----
    char* ws = (char*)d_ws;
    float*    h      = (float*)ws;                                   // MPAD*768 f32
    ushort_t* yb     = (ushort_t*)(ws + 38928384);                   // MPAD*768 bf16
    char*     Ubase  = ws + 58392576;                                 // shared region
    ushort_t* qkvb   = (ushort_t*)Ubase;                              // MPAD*2304 bf16
    ushort_t* ub     = (ushort_t*)Ubase;                              // MPAD*3072 bf16
    float*    peb    = (float*)Ubase;                                 // MP_*768 f32 (prologue)
    ushort_t* wqkv_t = (ushort_t*)(ws + 136249344);                   // 12*2304*768
    ushort_t* wp_t   = (ushort_t*)(ws + 178716672);                   // 12*768*768
    ushort_t* w1_t   = (ushort_t*)(ws + 192872448);                   // 12*3072*768
    ushort_t* w2_t   = (ushort_t*)(ws + 249495552);                   // 12*768*3072
    ushort_t* pwt    = (ushort_t*)(ws + 306118656);                   // 768*768
    float*    bqkv   = (float*)(ws + 307298304);                      // 12*2304 f32

    const dim3 blk(256);

    // ---- weight prep ----
    tcast_k<<<dim3(768 / 32, 768 / 32, 12), blk, 0, stream>>>(qw, wqkv_t,            768, 768, (size_t)768 * 768, (size_t)2304 * 768);
    tcast_k<<<dim3(768 / 32, 768 / 32, 12), blk, 0, stream>>>(kw, wqkv_t + 768 * 768, 768, 768, (size_t)768 * 768, (size_t)2304 * 768);
    tcast_k<<<dim3(768 / 32, 768 / 32, 12), blk, 0, stream>>>(vw, wqkv_t + 1536 * 768, 768, 768, (size_t)768 * 768, (size_t)2304 * 768);
    tcast_k<<<dim3(768 / 32, 768 / 32, 12), blk, 0, stream>>>(pw, wp_t, 768, 768, (size_t)768 * 768, (size_t)768 * 768);
    tcast_k<<<dim3(3072 / 32, 768 / 32, 12), blk, 0, stream>>>(fc1_w, w1_t, 768, 3072, (size_t)768 * 3072, (size_t)3072 * 768);
    tcast_k<<<dim3(768 / 32, 3072 / 32, 12), blk, 0, stream>>>(fc2_w, w2_t, 3072, 768, (size_t)3072 * 768, (size_t)768 * 3072);
    cast_k<<<dim3((768 * 768 + 255) / 256), blk, 0, stream>>>(patch_w, pwt, 768 * 768);
    biascat_k<<<dim3((DEPTH_ * 2304 + 255) / 256), blk, 0, stream>>>(qb, kb, vb, bqkv);
    zeroyb_k<<<dim3(((MPAD - M_) * 768 + 255) / 256), blk, 0, stream>>>(yb);

    // ---- patch embed ----
    im2col_k<<<dim3(((size_t)MP_ * 768 + 255) / 256), blk, 0, stream>>>(x, yb);
    mm_k<3><<<dim3(768 / BN, MP_ / BM), blk, 0, stream>>>(yb, pwt, patch_b, nullptr, peb, MP_, 768, 768);
    assemble_k<<<dim3(((size_t)MPAD * D_ + 255) / 256), blk, 0, stream>>>(peb, cls_tok, pos_emb, h);

    // ---- transformer blocks ----
    const dim3 gQKV(2304 / BN, MPAD / BM);
    const dim3 gD(768 / BN, MPAD / BM);
    const dim3 gFF(FF_ / BN, MPAD / BM);
    for (int l = 0; l < DEPTH_; ++l) {
        const size_t oDD = (size_t)l * 768 * 768;
        const size_t oD  = (size_t)l * 768;
        const size_t oDF = (size_t)l * 768 * FF_;
        const size_t oF  = (size_t)l * FF_;

        ln_k<true><<<dim3(M_), blk, 0, stream>>>(h, 768, yb, 768, ln1_s + oD, ln1_b + oD);
        mm_k<0><<<gQKV, blk, 0, stream>>>(yb, wqkv_t + (size_t)l * 2304 * 768, bqkv + (size_t)l * 2304, nullptr, qkvb, MPAD, 2304, 768);
        attn2_k<<<dim3(H_, B_), blk, 0, stream>>>(qkvb, yb);
        mm_k<2><<<gD, blk, 0, stream>>>(yb, wp_t + oDD, pb + oD, h, h, MPAD, 768, 768);
        ln_k<true><<<dim3(M_), blk, 0, stream>>>(h, 768, yb, 768, ln2_s + oD, ln2_b + oD);
        mm_k<1><<<gFF, blk, 0, stream>>>(yb, w1_t + oDF, fc1_b + oF, nullptr, ub, MPAD, FF_, 768);
        mm_k<2><<<gD, blk, 0, stream>>>(ub, w2_t + oDF, fc2_b + oD, h, h, MPAD, 768, FF_);
    }

    // ---- final LN on CLS rows ----
    ln_k<false><<<dim3(B_), blk, 0, stream>>>(h, (size_t)S_ * D_, out, 768, lnf_s, lnf_b);
}

// Round 4
// 5032.838 us; speedup vs baseline: 1.1700x; 1.1700x over previous
//
#include <hip/hip_runtime.h>
#include <math.h>

// ---- problem constants ----
constexpr int B_   = 64;
constexpr int S_   = 197;
constexpr int D_   = 768;
constexpr int H_   = 12;
constexpr int FF_  = 3072;
constexpr int DEPTH_ = 12;
constexpr int NP_  = 196;
constexpr int M_   = B_ * S_;    // 12608
constexpr int MP_  = B_ * NP_;   // 12544
constexpr int MR   = 12800;      // 50*256 padded rows

typedef __attribute__((ext_vector_type(8))) short  bf16x8;
typedef __attribute__((ext_vector_type(4))) float  f32x4;
typedef unsigned short ushort_t;

__device__ __forceinline__ ushort_t f2bf(float x) {
    unsigned u = __builtin_bit_cast(unsigned, x);
    unsigned r = u + 0x7FFFu + ((u >> 16) & 1u);
    return (ushort_t)(r >> 16);
}

#define GLOAD_LDS16(g, l)                                                      \
    __builtin_amdgcn_global_load_lds(                                          \
        (const __attribute__((address_space(1))) void*)(g),                    \
        (__attribute__((address_space(3))) void*)(l), 16, 0, 0)

// ============== 256x256 counted-vmcnt pipelined MFMA GEMM ==============
// C[M,N] = epi(A[M,K] @ Bt[N,K]^T + bias)   A,Bt bf16; acc f32.
// EPI: 0 = bf16 out, 1 = bf16 out + GELU, 2 = f32 out + residual, 3 = f32 out.
// M multiple of 256, N multiple of 256, K multiple of 128 (>=128).
// 512 threads = 8 waves (2 row-groups x 4 col-groups). K processed in
// 32-wide slices; 4 LDS slots (32KB each) hold slices j..j+3 (mod 4).
// Pipeline: stage slice j+3, vmcnt(12) [keeps 3 slices in flight], barrier,
// ds_read+MFMA slice j, barrier.  LDS bank-swizzle kq^=(row^row>>2)&3 applied
// on BOTH the pre-swizzled global source (write side, rule: gload_lds writes
// linearly) and the ds_read offset.

template<int EPI>
__global__ __launch_bounds__(512, 2)
void mm8_k(const ushort_t* __restrict__ A, const ushort_t* __restrict__ Bt,
           const float* __restrict__ bias, const float* __restrict__ res,
           void* __restrict__ Cout, int M, int N, int K) {
    __shared__ __align__(16) ushort_t lds[4 * 16384];   // 128 KiB
    const int tid  = threadIdx.x;
    const int wid  = tid >> 6;
    const int lane = tid & 63;

    // bijective XCD-chunked swizzle (m204)
    const int nwg  = gridDim.x * gridDim.y;
    const int orig = blockIdx.y * gridDim.x + blockIdx.x;
    const int xcd  = orig & 7, slot = orig >> 3;
    const int q8   = nwg >> 3, r8 = nwg & 7;
    const int logical = (xcd < r8 ? xcd * (q8 + 1) : r8 * (q8 + 1) + (xcd - r8) * q8) + slot;
    const int m0 = (logical / gridDim.x) * 256;
    const int n0 = (logical % gridDim.x) * 256;

    const int wr  = wid >> 2;        // 0..1  row half
    const int wcn = wid & 3;         // 0..3  col quarter
    const int l15 = lane & 15, kq = lane >> 4;
    const int swz  = (l15 ^ (l15 >> 2)) & 3;
    const int aoff = l15 * 64 + ((kq ^ swz) & 3) * 16;   // frag byte offset (A or B region)

    // stage-side: thread covers (row = tid>>2 [+128], kq' slot = tid&3)
    const int srow = tid >> 2;
    const int skq  = (tid & 3) ^ ((srow ^ (srow >> 2)) & 3);
    const size_t gA0 = (size_t)(m0 + srow) * K + skq * 8;
    const size_t gA1 = gA0 + (size_t)128 * K;
    const size_t gB0 = (size_t)(n0 + srow) * K + skq * 8;
    const size_t gB1 = gB0 + (size_t)128 * K;

    f32x4 acc[8][4];
    #pragma unroll
    for (int m = 0; m < 8; ++m)
        #pragma unroll
        for (int n = 0; n < 4; ++n)
            acc[m][n] = (f32x4){0.f, 0.f, 0.f, 0.f};

#define MM8_STAGE(jj)                                                          \
    { const int sl_ = (jj) & 3;                                                \
      const size_t kb_ = (size_t)(jj) * 32;                                    \
      GLOAD_LDS16(A  + gA0 + kb_, &lds[sl_ * 16384 + (wid * 64) * 8]);         \
      GLOAD_LDS16(A  + gA1 + kb_, &lds[sl_ * 16384 + (wid * 64 + 512) * 8]);   \
      GLOAD_LDS16(Bt + gB0 + kb_, &lds[sl_ * 16384 + 8192 + (wid * 64) * 8]);  \
      GLOAD_LDS16(Bt + gB1 + kb_, &lds[sl_ * 16384 + 8192 + (wid * 64 + 512) * 8]); }

#define MM8_PHASE(jj, VMC)                                                     \
    { asm volatile("s_waitcnt vmcnt(" VMC ")" ::: "memory");                   \
      __builtin_amdgcn_s_barrier();                                            \
      __builtin_amdgcn_sched_barrier(0);                                       \
      const char* Ab_ = (const char*)&lds[((jj) & 3) * 16384];                 \
      bf16x8 av[8], bv[4];                                                     \
      _Pragma("unroll")                                                        \
      for (int m = 0; m < 8; ++m)                                              \
          av[m] = *(const bf16x8*)(Ab_ + wr * 8192 + m * 1024 + aoff);         \
      _Pragma("unroll")                                                        \
      for (int n = 0; n < 4; ++n)                                              \
          bv[n] = *(const bf16x8*)(Ab_ + 16384 + wcn * 4096 + n * 1024 + aoff);\
      __builtin_amdgcn_s_setprio(1);                                           \
      _Pragma("unroll")                                                        \
      for (int m = 0; m < 8; ++m)                                              \
          _Pragma("unroll")                                                    \
          for (int n = 0; n < 4; ++n)                                          \
              acc[m][n] = __builtin_amdgcn_mfma_f32_16x16x32_bf16(av[m], bv[n], acc[m][n], 0, 0, 0); \
      __builtin_amdgcn_s_setprio(0);                                           \
      __builtin_amdgcn_sched_barrier(0);                                       \
      __builtin_amdgcn_s_barrier(); }

    const int NPH = K >> 5;
    MM8_STAGE(0); MM8_STAGE(1); MM8_STAGE(2);
    for (int j = 0; j + 3 < NPH; ++j) {
        MM8_STAGE(j + 3);
        MM8_PHASE(j, "12");
    }
    MM8_PHASE(NPH - 3, "8");
    MM8_PHASE(NPH - 2, "4");
    MM8_PHASE(NPH - 1, "0");
#undef MM8_STAGE
#undef MM8_PHASE

    // epilogue: C rows wr*128+m*16+(lane>>4)*4+j, cols wcn*64+n*16+l15
    #pragma unroll
    for (int n = 0; n < 4; ++n) {
        const int col = n0 + wcn * 64 + n * 16 + l15;
        const float bcol = bias[col];
        #pragma unroll
        for (int m = 0; m < 8; ++m) {
            #pragma unroll
            for (int j = 0; j < 4; ++j) {
                const int row = m0 + wr * 128 + m * 16 + (lane >> 4) * 4 + j;
                float v = acc[m][n][j] + bcol;
                if (EPI == 1) v = 0.5f * v * (1.0f + erff(v * 0.70710678118654752f));
                if (EPI == 2) v += res[(size_t)row * N + col];
                if (EPI <= 1) ((ushort_t*)Cout)[(size_t)row * N + col] = f2bf(v);
                else          ((float*)Cout)[(size_t)row * N + col] = v;
            }
        }
    }
}

// ====================== MFMA attention ======================
constexpr int SKV = 224;     // padded KV length (7 k-tiles of 32)
constexpr int VLD = 232;     // padded Vt row length (elements)

__global__ __launch_bounds__(256)
void attn2_k(const ushort_t* __restrict__ qkv, ushort_t* __restrict__ o) {
    __shared__ __align__(16) ushort_t Ks[SKV * 64];   // [j][dh], XOR-swizzled
    __shared__ __align__(16) ushort_t Vt[64 * VLD];   // [dh][j]
    __shared__ __align__(16) ushort_t Pw[4 * 512];    // per-wave 16x32, swizzled
    const int h = blockIdx.x, b = blockIdx.y;
    const int tid = threadIdx.x, wid = tid >> 6, lane = tid & 63;
    const size_t baseq = (size_t)(b * S_) * 2304 + h * 64;

    {
        const int jr  = tid >> 3;          // 0..31
        const int dh0 = (tid & 7) * 8;
        for (int pass = 0; pass < 7; ++pass) {
            const int j = pass * 32 + jr;
            bf16x8 kv = {0, 0, 0, 0, 0, 0, 0, 0};
            bf16x8 vv = {0, 0, 0, 0, 0, 0, 0, 0};
            if (j < S_) {
                kv = *(const bf16x8*)&qkv[baseq + (size_t)j * 2304 + 768  + dh0];
                vv = *(const bf16x8*)&qkv[baseq + (size_t)j * 2304 + 1536 + dh0];
            }
            const int koff = (j * 128 + dh0 * 2) ^ ((j & 7) << 4);
            *(bf16x8*)((char*)Ks + koff) = kv;
            #pragma unroll
            for (int i = 0; i < 8; ++i) Vt[(dh0 + i) * VLD + j] = (ushort_t)vv[i];
        }
    }
    __syncthreads();

    char* const pwb = (char*)Pw + wid * 1024;

    for (int it = 0; it < 4; ++it) {
        int sq = it * 64 + wid * 16 + (lane & 15);
        const int sqc = (sq < S_) ? sq : (S_ - 1);
        bf16x8 qf[2];
        #pragma unroll
        for (int kk = 0; kk < 2; ++kk)
            qf[kk] = *(const bf16x8*)&qkv[baseq + (size_t)sqc * 2304 + kk * 32 + (lane >> 4) * 8];

        f32x4 sa[14];
        #pragma unroll
        for (int nf = 0; nf < 14; ++nf) sa[nf] = (f32x4){0.f, 0.f, 0.f, 0.f};
        #pragma unroll
        for (int kk = 0; kk < 2; ++kk) {
            #pragma unroll
            for (int nf = 0; nf < 14; ++nf) {
                const int j = nf * 16 + (lane & 15);
                const int off = (j * 128 + kk * 64 + (lane >> 4) * 16) ^ ((j & 7) << 4);
                bf16x8 kf = *(const bf16x8*)((const char*)Ks + off);
                sa[nf] = __builtin_amdgcn_mfma_f32_16x16x32_bf16(qf[kk], kf, sa[nf], 0, 0, 0);
            }
        }

        const int jcol = lane & 15;
        float mx[4] = {-1e30f, -1e30f, -1e30f, -1e30f};
        #pragma unroll
        for (int nf = 0; nf < 14; ++nf)
            #pragma unroll
            for (int r = 0; r < 4; ++r) mx[r] = fmaxf(mx[r], sa[nf][r]);
        float ls[4];
        #pragma unroll
        for (int r = 0; r < 4; ++r) {
            float m = mx[r] * 0.125f;
            m = fmaxf(m, __shfl_xor(m, 1, 64));
            m = fmaxf(m, __shfl_xor(m, 2, 64));
            m = fmaxf(m, __shfl_xor(m, 4, 64));
            m = fmaxf(m, __shfl_xor(m, 8, 64));
            float s = 0.f;
            #pragma unroll
            for (int nf = 0; nf < 14; ++nf) {
                const int j = nf * 16 + jcol;
                float p = (j < S_) ? exp2f((sa[nf][r] * 0.125f - m) * 1.44269504088896f) : 0.f;
                sa[nf][r] = p;
                s += p;
            }
            s += __shfl_xor(s, 1, 64);
            s += __shfl_xor(s, 2, 64);
            s += __shfl_xor(s, 4, 64);
            s += __shfl_xor(s, 8, 64);
            ls[r] = s;
        }

        f32x4 oa[4];
        #pragma unroll
        for (int nf = 0; nf < 4; ++nf) oa[nf] = (f32x4){0.f, 0.f, 0.f, 0.f};
        #pragma unroll
        for (int kt = 0; kt < 7; ++kt) {
            #pragma unroll
            for (int half = 0; half < 2; ++half) {
                #pragma unroll
                for (int r = 0; r < 4; ++r) {
                    const int qr = (lane >> 4) * 4 + r;
                    const int jl = half * 16 + jcol;
                    const int off = (qr * 64 + jl * 2) ^ (((qr >> 1) & 3) << 4);
                    *(ushort_t*)(pwb + off) = f2bf(sa[kt * 2 + half][r]);
                }
            }
            const int arow = lane & 15;
            const int aoff2 = (arow * 64 + (lane >> 4) * 16) ^ (((arow >> 1) & 3) << 4);
            bf16x8 pa = *(const bf16x8*)(pwb + aoff2);
            #pragma unroll
            for (int nf = 0; nf < 4; ++nf) {
                const int dh = nf * 16 + (lane & 15);
                bf16x8 vb = *(const bf16x8*)((const char*)Vt + dh * (VLD * 2) + (kt * 32 + (lane >> 4) * 8) * 2);
                oa[nf] = __builtin_amdgcn_mfma_f32_16x16x32_bf16(pa, vb, oa[nf], 0, 0, 0);
            }
        }

        #pragma unroll
        for (int r = 0; r < 4; ++r) {
            const int so = it * 64 + wid * 16 + (lane >> 4) * 4 + r;
            if (so < S_) {
                const float inv = 1.0f / ls[r];
                #pragma unroll
                for (int nf = 0; nf < 4; ++nf)
                    o[(size_t)(b * S_ + so) * 768 + h * 64 + nf * 16 + (lane & 15)] = f2bf(oa[nf][r] * inv);
            }
        }
    }
}

// ====================== small kernels ======================
__global__ __launch_bounds__(256)
void tcast_k(const float* __restrict__ in, ushort_t* __restrict__ out,
             int R, int C, size_t in_ls, size_t out_ls) {
    __shared__ float t[32][33];
    const float* ip = in + (size_t)blockIdx.z * in_ls;
    ushort_t* op = out + (size_t)blockIdx.z * out_ls;
    const int c0 = blockIdx.x * 32, r0 = blockIdx.y * 32;
    const int tx = threadIdx.x & 31, ty = threadIdx.x >> 5;
    #pragma unroll
    for (int i = 0; i < 4; ++i)
        t[ty + i * 8][tx] = ip[(size_t)(r0 + ty + i * 8) * C + c0 + tx];
    __syncthreads();
    #pragma unroll
    for (int i = 0; i < 4; ++i)
        op[(size_t)(c0 + ty + i * 8) * R + r0 + tx] = f2bf(t[tx][ty + i * 8]);
}

__global__ void cast_k(const float* __restrict__ in, ushort_t* __restrict__ out, int n) {
    int i = blockIdx.x * 256 + threadIdx.x;
    if (i < n) out[i] = f2bf(in[i]);
}

__global__ void biascat_k(const float* __restrict__ qb, const float* __restrict__ kb,
                          const float* __restrict__ vb, float* __restrict__ out) {
    int i = blockIdx.x * 256 + threadIdx.x;       // l*2304 + n
    if (i >= DEPTH_ * 2304) return;
    int l = i / 2304, n = i % 2304;
    float v = (n < 768) ? qb[l * 768 + n] : (n < 1536) ? kb[l * 768 + n - 768] : vb[l * 768 + n - 1536];
    out[i] = v;
}

__global__ void im2col_k(const float* __restrict__ x, ushort_t* __restrict__ pm) {
    size_t idx = (size_t)blockIdx.x * 256 + threadIdx.x;
    if (idx >= (size_t)MP_ * 768) return;
    int col = (int)(idx % 768);
    int row = (int)(idx / 768);
    int b = row / NP_, p = row % NP_;
    int c = col >> 8, rem = col & 255, ky = rem >> 4, kx = rem & 15;
    int py = p / 14, px = p % 14;
    pm[idx] = f2bf(x[(((size_t)b * 3 + c) * 224 + (py * 16 + ky)) * 224 + (px * 16 + kx)]);
}

__global__ void assemble_k(const float* __restrict__ pe, const float* __restrict__ cls,
                           const float* __restrict__ pos, float* __restrict__ h) {
    size_t idx = (size_t)blockIdx.x * 256 + threadIdx.x;
    if (idx >= (size_t)M_ * D_) return;
    int d = (int)(idx % D_);
    int row = (int)(idx / D_);
    int b = row / S_, s = row % S_;
    float v;
    if (s == 0) v = cls[d] + pos[d];
    else        v = pe[((size_t)b * NP_ + (s - 1)) * D_ + d] + pos[(size_t)s * D_ + d];
    h[idx] = v;
}

__device__ __forceinline__ float block_reduce_sum(float val) {
    __shared__ float sm[4];
    #pragma unroll
    for (int off = 32; off > 0; off >>= 1) val += __shfl_xor(val, off, 64);
    int wid = threadIdx.x >> 6;
    if ((threadIdx.x & 63) == 0) sm[wid] = val;
    __syncthreads();
    float r = (sm[0] + sm[1]) + (sm[2] + sm[3]);
    __syncthreads();
    return r;
}

template<bool BF16OUT>
__global__ __launch_bounds__(256)
void ln_k(const float* __restrict__ x, size_t xstride,
          void* __restrict__ y, size_t ystride,
          const float* __restrict__ s, const float* __restrict__ b) {
    const float* xr = x + (size_t)blockIdx.x * xstride;
    const int tid = threadIdx.x;
    float v[3];
    float sum = 0.f;
    #pragma unroll
    for (int t = 0; t < 3; ++t) { v[t] = xr[tid + t * 256]; sum += v[t]; }
    sum = block_reduce_sum(sum);
    const float mu = sum * (1.0f / 768.0f);
    float vs = 0.f;
    #pragma unroll
    for (int t = 0; t < 3; ++t) { float d = v[t] - mu; vs += d * d; }
    vs = block_reduce_sum(vs);
    const float rstd = rsqrtf(vs * (1.0f / 768.0f) + 1e-6f);
    #pragma unroll
    for (int t = 0; t < 3; ++t) {
        int c = tid + t * 256;
        float r = (v[t] - mu) * rstd * s[c] + b[c];
        if (BF16OUT) ((ushort_t*)y)[(size_t)blockIdx.x * ystride + c] = f2bf(r);
        else         ((float*)y)[(size_t)blockIdx.x * ystride + c] = r;
    }
}

// ====================== launch ======================
extern "C" void kernel_launch(void* const* d_in, const int* in_sizes, int n_in,
                              void* d_out, int out_size, void* d_ws, size_t ws_size,
                              hipStream_t stream) {
    const float* x       = (const float*)d_in[0];
    const float* patch_w = (const float*)d_in[1];
    const float* patch_b = (const float*)d_in[2];
    const float* cls_tok = (const float*)d_in[3];
    const float* pos_emb = (const float*)d_in[4];
    const float* ln1_s   = (const float*)d_in[5];
    const float* ln1_b   = (const float*)d_in[6];
    const float* qw      = (const float*)d_in[7];
    const float* qb      = (const float*)d_in[8];
    const float* kw      = (const float*)d_in[9];
    const float* kb      = (const float*)d_in[10];
    const float* vw      = (const float*)d_in[11];
    const float* vb      = (const float*)d_in[12];
    const float* pw      = (const float*)d_in[13];
    const float* pb      = (const float*)d_in[14];
    const float* ln2_s   = (const float*)d_in[15];
    const float* ln2_b   = (const float*)d_in[16];
    const float* fc1_w   = (const float*)d_in[17];
    const float* fc1_b   = (const float*)d_in[18];
    const float* fc2_w   = (const float*)d_in[19];
    const float* fc2_b   = (const float*)d_in[20];
    const float* lnf_s   = (const float*)d_in[21];
    const float* lnf_b   = (const float*)d_in[22];
    float* out = (float*)d_out;

    // ---- workspace layout (bytes) ----
    char* ws = (char*)d_ws;
    float*    h      = (float*)ws;                                   // MR*768 f32
    ushort_t* yb     = (ushort_t*)(ws + 39321600);                   // MR*768 bf16
    char*     Ubase  = ws + 58982400;                                 // shared region (MR*3072 bf16 max)
    ushort_t* qkvb   = (ushort_t*)Ubase;                              // MR*2304 bf16
    ushort_t* ub     = (ushort_t*)Ubase;                              // MR*3072 bf16
    float*    peb    = (float*)Ubase;                                 // MR*768 f32 (prologue)
    ushort_t* wqkv_t = (ushort_t*)(ws + 137625600);                   // 12*2304*768
    ushort_t* wp_t   = (ushort_t*)(ws + 180092928);                   // 12*768*768
    ushort_t* w1_t   = (ushort_t*)(ws + 194248704);                   // 12*3072*768
    ushort_t* w2_t   = (ushort_t*)(ws + 250871808);                   // 12*768*3072
    ushort_t* pwt    = (ushort_t*)(ws + 307494912);                   // 768*768
    float*    bqkv   = (float*)(ws + 308674560);                      // 12*2304 f32

    const dim3 blk(256);
    const dim3 blk512(512);

    // ---- weight prep ----
    tcast_k<<<dim3(768 / 32, 768 / 32, 12), blk, 0, stream>>>(qw, wqkv_t,            768, 768, (size_t)768 * 768, (size_t)2304 * 768);
    tcast_k<<<dim3(768 / 32, 768 / 32, 12), blk, 0, stream>>>(kw, wqkv_t + 768 * 768, 768, 768, (size_t)768 * 768, (size_t)2304 * 768);
    tcast_k<<<dim3(768 / 32, 768 / 32, 12), blk, 0, stream>>>(vw, wqkv_t + 1536 * 768, 768, 768, (size_t)768 * 768, (size_t)2304 * 768);
    tcast_k<<<dim3(768 / 32, 768 / 32, 12), blk, 0, stream>>>(pw, wp_t, 768, 768, (size_t)768 * 768, (size_t)768 * 768);
    tcast_k<<<dim3(3072 / 32, 768 / 32, 12), blk, 0, stream>>>(fc1_w, w1_t, 768, 3072, (size_t)768 * 3072, (size_t)3072 * 768);
    tcast_k<<<dim3(768 / 32, 3072 / 32, 12), blk, 0, stream>>>(fc2_w, w2_t, 3072, 768, (size_t)3072 * 768, (size_t)768 * 3072);
    cast_k<<<dim3((768 * 768 + 255) / 256), blk, 0, stream>>>(patch_w, pwt, 768 * 768);
    biascat_k<<<dim3((DEPTH_ * 2304 + 255) / 256), blk, 0, stream>>>(qb, kb, vb, bqkv);

    // ---- patch embed ----
    im2col_k<<<dim3(((size_t)MP_ * 768 + 255) / 256), blk, 0, stream>>>(x, yb);
    mm8_k<3><<<dim3(3, MR / 256), blk512, 0, stream>>>(yb, pwt, patch_b, nullptr, peb, MR, 768, 768);
    assemble_k<<<dim3(((size_t)M_ * D_ + 255) / 256), blk, 0, stream>>>(peb, cls_tok, pos_emb, h);

    // ---- transformer blocks ----
    const dim3 gQKV(9, MR / 256);
    const dim3 gD(3, MR / 256);
    const dim3 gFF(12, MR / 256);
    for (int l = 0; l < DEPTH_; ++l) {
        const size_t oDD = (size_t)l * 768 * 768;
        const size_t oD  = (size_t)l * 768;
        const size_t oDF = (size_t)l * 768 * FF_;
        const size_t oF  = (size_t)l * FF_;

        ln_k<true><<<dim3(M_), blk, 0, stream>>>(h, 768, yb, 768, ln1_s + oD, ln1_b + oD);
        mm8_k<0><<<gQKV, blk512, 0, stream>>>(yb, wqkv_t + (size_t)l * 2304 * 768, bqkv + (size_t)l * 2304, nullptr, qkvb, MR, 2304, 768);
        attn2_k<<<dim3(H_, B_), blk, 0, stream>>>(qkvb, yb);
        mm8_k<2><<<gD, blk512, 0, stream>>>(yb, wp_t + oDD, pb + oD, h, h, MR, 768, 768);
        ln_k<true><<<dim3(M_), blk, 0, stream>>>(h, 768, yb, 768, ln2_s + oD, ln2_b + oD);
        mm8_k<1><<<gFF, blk512, 0, stream>>>(yb, w1_t + oDF, fc1_b + oF, nullptr, ub, MR, FF_, 768);
        mm8_k<2><<<gD, blk512, 0, stream>>>(ub, w2_t + oDF, fc2_b + oD, h, h, MR, 768, FF_);
    }

    // ---- final LN on CLS rows ----
    ln_k<false><<<dim3(B_), blk, 0, stream>>>(h, (size_t)S_ * D_, out, 768, lnf_s, lnf_b);
}